// Round 5
// baseline (3935.080 us; speedup 1.0000x reference)
//
#include <hip/hip_runtime.h>
#include <math.h>

#define B_ 128
#define V_ 32
#define D_ 64
#define H_ 256
#define E_ 992
#define ME (B_*E_)   // 126976
#define MV (B_*V_)   // 4096

typedef __attribute__((ext_vector_type(8))) short bf8v;       // 8 bf16 fragment
typedef __attribute__((ext_vector_type(4))) float f4v;        // MFMA accumulator
typedef __attribute__((ext_vector_type(8))) unsigned short u16x8;

__device__ __forceinline__ unsigned short f2bf(float f) {
    union { float f; unsigned int u; } v; v.f = f;
    unsigned int u = v.u + 0x7FFFu + ((v.u >> 16) & 1u);   // RNE
    return (unsigned short)(u >> 16);
}
__device__ __forceinline__ float bf2f(unsigned short h) {
    union { unsigned int u; float f; } v; v.u = ((unsigned int)h) << 16;
    return v.f;
}
__device__ __forceinline__ float sigf(float x) {
    x = fminf(fmaxf(x, -30.f), 30.f);
    return 1.f / (1.f + __expf(-x));
}
__device__ __forceinline__ float tanhf_fast(float x) {
    x = fminf(fmaxf(x, -15.f), 15.f);
    float e = __expf(2.f * x);
    return (e - 1.f) / (e + 1.f);
}

// T-tile swizzle (64 rows x 256 cols bf16): 16B granule XOR'd by row&7.
// a-frag reads (16 rows, same k) land 2-way on banks => conflict-free.
__device__ __forceinline__ int tidx(int row, int k) {
    return row * 256 + (k ^ ((row & 7) << 3));
}

// ---------------------------------------------------------------------------
// Weight conversions, batched.  convW7: seven 256x256 mats -> contiguous dst.
// y==2 is the m4w1[:,512:768] slice (ld 768).
// ---------------------------------------------------------------------------
__global__ __launch_bounds__(256)
void convW7_k(const float* __restrict__ s0, const float* __restrict__ s1,
              const float* __restrict__ s2, const float* __restrict__ s3,
              const float* __restrict__ s4, const float* __restrict__ s5,
              const float* __restrict__ s6, unsigned short* __restrict__ d)
{
    const int y = blockIdx.y;
    const int g = blockIdx.x * 256 + threadIdx.x;   // 0..16383 float4s
    float4 v;
    if (y == 2) {
        const int r = g >> 6, c4 = (g & 63) * 4;
        v = *(const float4*)(s2 + (size_t)r * 768 + 512 + c4);
    } else {
        const float* s = (y == 0) ? s0 : (y == 1) ? s1 : (y == 3) ? s3 :
                         (y == 4) ? s4 : (y == 5) ? s5 : s6;
        v = ((const float4*)s)[g];
    }
    ushort4 o;
    o.x = f2bf(v.x); o.y = f2bf(v.y); o.z = f2bf(v.z); o.w = f2bf(v.w);
    ((ushort4*)(d + (size_t)y * 65536))[g] = o;
}

__global__ __launch_bounds__(256)
void convIH_k(const float* __restrict__ wih, const float* __restrict__ whh,
              unsigned short* __restrict__ d)
{
    const int y = blockIdx.y;
    const int g = blockIdx.x * 256 + threadIdx.x;   // 0..65535 float4s
    const float4 v = ((const float4*)(y ? whh : wih))[g];
    ushort4 o;
    o.x = f2bf(v.x); o.y = f2bf(v.y); o.z = f2bf(v.z); o.w = f2bf(v.w);
    ((ushort4*)(d + (size_t)y * 262144))[g] = o;
}

__global__ __launch_bounds__(256)
void f2b_k(const float* __restrict__ s, unsigned short* __restrict__ d, int n4)
{
    const int g = blockIdx.x * 256 + threadIdx.x;
    if (g >= n4) return;
    const float4 v = ((const float4*)s)[g];
    ushort4 o;
    o.x = f2bf(v.x); o.y = f2bf(v.y); o.z = f2bf(v.z); o.w = f2bf(v.w);
    ((ushort4*)d)[g] = o;
}

// ---------------------------------------------------------------------------
// fp32 VALU GEMM (node path, M=4096)
// ---------------------------------------------------------------------------
__global__ __launch_bounds__(256)
void gemm_k(const float* __restrict__ A, int lda,
            const float* __restrict__ W, int ldw,
            const float* __restrict__ bias,
            float* __restrict__ out,
            int M, int N, int K, int do_relu)
{
    __shared__ float As[32][68];
    __shared__ float Ws[32][68];
    const int m0 = blockIdx.x * 64;
    const int n0 = blockIdx.y * 64;
    const int t  = threadIdx.x;
    const int tx = t & 15, ty = t >> 4;
    const int lm = t >> 3;
    const int lk = (t & 7) * 4;

    float acc[4][4] = {};

    for (int k0 = 0; k0 < K; k0 += 32) {
        #pragma unroll
        for (int h = 0; h < 2; ++h) {
            const int m = m0 + lm + h * 32;
            const float4 v = *(const float4*)(A + (size_t)m * lda + k0 + lk);
            As[lk + 0][lm + h * 32] = v.x;
            As[lk + 1][lm + h * 32] = v.y;
            As[lk + 2][lm + h * 32] = v.z;
            As[lk + 3][lm + h * 32] = v.w;
            const int n = n0 + lm + h * 32;
            const float4 w = *(const float4*)(W + (size_t)n * ldw + k0 + lk);
            Ws[lk + 0][lm + h * 32] = w.x;
            Ws[lk + 1][lm + h * 32] = w.y;
            Ws[lk + 2][lm + h * 32] = w.z;
            Ws[lk + 3][lm + h * 32] = w.w;
        }
        __syncthreads();
        #pragma unroll
        for (int kk = 0; kk < 32; ++kk) {
            float a[4], b[4];
            #pragma unroll
            for (int i = 0; i < 4; ++i) a[i] = As[kk][ty * 4 + i];
            #pragma unroll
            for (int j = 0; j < 4; ++j) b[j] = Ws[kk][tx * 4 + j];
            #pragma unroll
            for (int i = 0; i < 4; ++i)
                #pragma unroll
                for (int j = 0; j < 4; ++j)
                    acc[i][j] = fmaf(a[i], b[j], acc[i][j]);
        }
        __syncthreads();
    }

    #pragma unroll
    for (int i = 0; i < 4; ++i) {
        const int m = m0 + ty * 4 + i;
        const size_t ob = (size_t)m * N;
        #pragma unroll
        for (int j = 0; j < 4; ++j) {
            const int n = n0 + tx * 4 + j;
            float v = acc[i][j];
            if (bias) v += bias[n];
            if (do_relu) v = fmaxf(v, 0.f);
            out[ob + n] = v;
        }
    }
}

// ---------------------------------------------------------------------------
// In-LDS GEMM layer, register-streamed weights (NO barriers in K-loop).
// T[64,256] bf16 swizzled. 256 thr / 4 waves; wave c owns cols c*64..c*64+63.
// B-frags loaded global->reg (W is L2-resident, 128KB/layer). 2 barriers total.
// ---------------------------------------------------------------------------
template<int RELU, int EPI>
__device__ __forceinline__ void chain_layer(
    unsigned short* T,
    const unsigned short* __restrict__ W, const float* __restrict__ bias,
    int m0, const float* __restrict__ ES, const float* __restrict__ ER)
{
    const int t = threadIdx.x, lane = t & 63, c = t >> 6;
    const int laneN = lane & 15, kof = (lane >> 4) * 8;
    const unsigned short* wb = W + (size_t)(c * 64 + laneN) * 256 + kof;

    f4v acc[4][4];
    #pragma unroll
    for (int i = 0; i < 4; ++i)
        #pragma unroll
        for (int j = 0; j < 4; ++j)
            acc[i][j] = (f4v){0.f, 0.f, 0.f, 0.f};

    bf8v bc[4];
    #pragma unroll
    for (int f = 0; f < 4; ++f) bc[f] = *(const bf8v*)(wb + f * 4096);

    #pragma unroll
    for (int s = 0; s < 8; ++s) {
        bf8v bn[4];
        if (s < 7) {
            #pragma unroll
            for (int f = 0; f < 4; ++f) bn[f] = *(const bf8v*)(wb + f * 4096 + (s + 1) * 32);
        }
        bf8v a[4];
        #pragma unroll
        for (int i = 0; i < 4; ++i) a[i] = *(const bf8v*)&T[tidx(i * 16 + laneN, s * 32 + kof)];
        #pragma unroll
        for (int i = 0; i < 4; ++i)
            #pragma unroll
            for (int j = 0; j < 4; ++j)
                acc[i][j] = __builtin_amdgcn_mfma_f32_16x16x32_bf16(a[i], bc[j], acc[i][j], 0, 0, 0);
        #pragma unroll
        for (int f = 0; f < 4; ++f) bc[f] = bn[f];
    }

    __syncthreads();   // all reads of T done

    float bv[4];
    #pragma unroll
    for (int j = 0; j < 4; ++j) bv[j] = bias[c * 64 + j * 16 + laneN];

    #pragma unroll
    for (int i = 0; i < 4; ++i) {
        #pragma unroll
        for (int reg = 0; reg < 4; ++reg) {
            const int row = i * 16 + (lane >> 4) * 4 + reg;
            size_t bs = 0, br = 0;
            if (EPI) {
                const int m  = m0 + row;
                const int bb = m / E_;
                const int e  = m - bb * E_;
                const int sS = e / 31;
                const int jj = e - sS * 31;
                const int rr = jj + (jj >= sS ? 1 : 0);
                bs = ((size_t)bb * V_ + sS) * H_;
                br = ((size_t)bb * V_ + rr) * H_;
            }
            #pragma unroll
            for (int j = 0; j < 4; ++j) {
                const int n = c * 64 + j * 16 + laneN;
                float v = acc[i][j][reg] + bv[j];
                if (EPI) v += ES[bs + n] + ER[br + n];
                if (RELU) v = fmaxf(v, 0.f);
                T[tidx(row, n)] = f2bf(v);
            }
        }
    }
    __syncthreads();   // T ready for next layer
}

// ---------------------------------------------------------------------------
// LSTM pass jc (of 4): 64 rows x (4 gates x 16 j). K=512: x4 from T (LDS),
// h0 global->reg. W global->reg. NO barriers at all.
// ---------------------------------------------------------------------------
__device__ __forceinline__ void lstm_pass(
    const unsigned short* T,
    const unsigned short* __restrict__ h0b,
    const unsigned short* __restrict__ wih, const unsigned short* __restrict__ whh,
    const float* __restrict__ bih, const float* __restrict__ bhh,
    const float* __restrict__ c0,
    float* __restrict__ h1, float* __restrict__ c1, unsigned short* __restrict__ h1b,
    int m0, int jc)
{
    const int t = threadIdx.x, lane = t & 63, c = t >> 6;
    const int laneN = lane & 15, kof = (lane >> 4) * 8;
    const unsigned short* wbi = wih + (size_t)(jc * 64 + c * 16 + laneN) * 256 + kof;
    const unsigned short* wbh = whh + (size_t)(jc * 64 + c * 16 + laneN) * 256 + kof;
    const unsigned short* ab  = h0b + (size_t)(m0 + laneN) * 256 + kof;

    f4v acc[4][4];
    #pragma unroll
    for (int i = 0; i < 4; ++i)
        #pragma unroll
        for (int g = 0; g < 4; ++g)
            acc[i][g] = (f4v){0.f, 0.f, 0.f, 0.f};

    bf8v bc[4];
    #pragma unroll
    for (int g = 0; g < 4; ++g) bc[g] = *(const bf8v*)(wbi + (size_t)g * 65536);

    #pragma unroll
    for (int s = 0; s < 16; ++s) {
        bf8v bn[4];
        if (s < 15) {
            const int s2 = s + 1;
            #pragma unroll
            for (int g = 0; g < 4; ++g)
                bn[g] = (s2 < 8) ? *(const bf8v*)(wbi + (size_t)g * 65536 + s2 * 32)
                                 : *(const bf8v*)(wbh + (size_t)g * 65536 + (s2 - 8) * 32);
        }
        bf8v a[4];
        #pragma unroll
        for (int i = 0; i < 4; ++i) {
            if (s < 8) a[i] = *(const bf8v*)&T[tidx(i * 16 + laneN, s * 32 + kof)];
            else       a[i] = *(const bf8v*)(ab + (size_t)i * 4096 + (s - 8) * 32);
        }
        #pragma unroll
        for (int i = 0; i < 4; ++i)
            #pragma unroll
            for (int g = 0; g < 4; ++g)
                acc[i][g] = __builtin_amdgcn_mfma_f32_16x16x32_bf16(a[i], bc[g], acc[i][g], 0, 0, 0);
        #pragma unroll
        for (int g = 0; g < 4; ++g) bc[g] = bn[g];
    }

    const int j = jc * 64 + c * 16 + laneN;
    const float bi0 = bih[j]       + bhh[j];
    const float bi1 = bih[256 + j] + bhh[256 + j];
    const float bi2 = bih[512 + j] + bhh[512 + j];
    const float bi3 = bih[768 + j] + bhh[768 + j];
    #pragma unroll
    for (int i = 0; i < 4; ++i) {
        #pragma unroll
        for (int reg = 0; reg < 4; ++reg) {
            const int row = i * 16 + (lane >> 4) * 4 + reg;
            const size_t o = (size_t)(m0 + row) * 256 + j;
            const float gi = acc[i][0][reg] + bi0;
            const float gf = acc[i][1][reg] + bi1;
            const float gg = acc[i][2][reg] + bi2;
            const float go = acc[i][3][reg] + bi3;
            const float cn = sigf(gf) * c0[o] + sigf(gi) * tanhf_fast(gg);
            const float hn = sigf(go) * tanhf_fast(cn);
            c1[o] = cn;
            h1[o] = hn;
            h1b[o] = f2bf(hn);
        }
    }
}

// ---------------------------------------------------------------------------
// chain1: T = relu(Ys[send]+Yr[recv]+b1); two GEMM layers; export X2.
// ---------------------------------------------------------------------------
__global__ __launch_bounds__(256, 3)
void chain1_k(const float* __restrict__ Ys, const float* __restrict__ Yr,
              const float* __restrict__ b1,
              const unsigned short* __restrict__ w2, const float* __restrict__ b2,
              const unsigned short* __restrict__ w3, const float* __restrict__ b3,
              unsigned short* __restrict__ X2out)
{
    __shared__ alignas(16) unsigned short T[16384];   // 32KB
    const int t  = threadIdx.x;
    const int m0 = blockIdx.x * 64;

    #pragma unroll
    for (int it = 0; it < 16; ++it) {
        const int q   = it * 256 + t;
        const int row = q >> 6;
        const int n4  = (q & 63) * 4;
        const int m  = m0 + row;
        const int bb = m / E_;
        const int e  = m - bb * E_;
        const int s  = e / 31;
        const int jj = e - s * 31;
        const int rv = jj + (jj >= s ? 1 : 0);
        const float4 ys = *(const float4*)&Ys[((size_t)bb * V_ + s)  * H_ + n4];
        const float4 yr = *(const float4*)&Yr[((size_t)bb * V_ + rv) * H_ + n4];
        const float4 bx = *(const float4*)&b1[n4];
        ushort4 o;
        o.x = f2bf(fmaxf(ys.x + yr.x + bx.x, 0.f));
        o.y = f2bf(fmaxf(ys.y + yr.y + bx.y, 0.f));
        o.z = f2bf(fmaxf(ys.z + yr.z + bx.z, 0.f));
        o.w = f2bf(fmaxf(ys.w + yr.w + bx.w, 0.f));
        *(ushort4*)&T[tidx(row, n4)] = o;
    }
    __syncthreads();

    chain_layer<1, 0>(T, w2, b2, m0, nullptr, nullptr);
    chain_layer<0, 0>(T, w3, b3, m0, nullptr, nullptr);

    #pragma unroll
    for (int it = 0; it < 8; ++it) {
        const int g   = it * 256 + t;
        const int row = g >> 5;
        const int kp  = (g & 31) * 8;
        *(u16x8*)&X2out[(size_t)(m0 + row) * 256 + kp] = *(const u16x8*)&T[tidx(row, kp)];
    }
}

// ---------------------------------------------------------------------------
// chain2: MLP4 (3 layers, L1 + Zs/Zr gather) + fused LSTM (4 passes).
// ---------------------------------------------------------------------------
__global__ __launch_bounds__(256, 3)
void chain2_k(const unsigned short* __restrict__ X2,
              const unsigned short* __restrict__ w41, const float* __restrict__ b41,
              const unsigned short* __restrict__ w42, const float* __restrict__ b42,
              const unsigned short* __restrict__ w43, const float* __restrict__ b43,
              const float* __restrict__ ZS, const float* __restrict__ ZR,
              const unsigned short* __restrict__ h0b,
              const unsigned short* __restrict__ wih, const unsigned short* __restrict__ whh,
              const float* __restrict__ bih, const float* __restrict__ bhh,
              const float* __restrict__ c0,
              float* __restrict__ h1, float* __restrict__ c1,
              unsigned short* __restrict__ h1b)
{
    __shared__ alignas(16) unsigned short T[16384];
    const int t  = threadIdx.x;
    const int m0 = blockIdx.x * 64;

    #pragma unroll
    for (int it = 0; it < 8; ++it) {
        const int g   = it * 256 + t;
        const int row = g >> 5;
        const int kp  = (g & 31) * 8;
        *(u16x8*)&T[tidx(row, kp)] = *(const u16x8*)&X2[(size_t)(m0 + row) * 256 + kp];
    }
    __syncthreads();

    chain_layer<1, 1>(T, w41, b41, m0, ZS, ZR);
    chain_layer<1, 0>(T, w42, b42, m0, nullptr, nullptr);
    chain_layer<0, 0>(T, w43, b43, m0, nullptr, nullptr);

    #pragma unroll
    for (int jc = 0; jc < 4; ++jc)
        lstm_pass(T, h0b, wih, whh, bih, bhh, c0, h1, c1, h1b, m0, jc);
}

// ---------------------------------------------------------------------------
// prior chain: h1b -> pw1 -> pw2 -> pw3 (2 cols).
// ---------------------------------------------------------------------------
__global__ __launch_bounds__(256, 3)
void prior_k(const unsigned short* __restrict__ Hin,
             const unsigned short* __restrict__ w1, const float* __restrict__ b1,
             const unsigned short* __restrict__ w2, const float* __restrict__ b2,
             const float* __restrict__ w3, const float* __restrict__ b3,
             float* __restrict__ out)
{
    __shared__ alignas(16) unsigned short T[16384];
    const int t  = threadIdx.x;
    const int m0 = blockIdx.x * 64;

    #pragma unroll
    for (int it = 0; it < 8; ++it) {
        const int g   = it * 256 + t;
        const int row = g >> 5;
        const int kp  = (g & 31) * 8;
        *(u16x8*)&T[tidx(row, kp)] = *(const u16x8*)&Hin[(size_t)(m0 + row) * 256 + kp];
    }
    __syncthreads();

    chain_layer<1, 0>(T, w1, b1, m0, nullptr, nullptr);
    chain_layer<1, 0>(T, w2, b2, m0, nullptr, nullptr);

    // final 2-col layer: 4 threads per row, 64 k each
    const int row = t >> 2;
    const int kb  = (t & 3) * 64;
    float p0 = 0.f, p1 = 0.f;
    #pragma unroll
    for (int g = 0; g < 8; ++g) {
        const int k = kb + g * 8;
        const u16x8 v = *(const u16x8*)&T[tidx(row, k)];
        #pragma unroll
        for (int i = 0; i < 8; ++i) {
            const float x = bf2f(v[i]);
            p0 += x * w3[k + i];
            p1 += x * w3[256 + k + i];
        }
    }
    p0 += __shfl_xor(p0, 1); p0 += __shfl_xor(p0, 2);
    p1 += __shfl_xor(p1, 1); p1 += __shfl_xor(p1, 2);
    if ((t & 3) == 0) {
        out[(size_t)(m0 + row) * 2 + 0] = p0 + b3[0];
        out[(size_t)(m0 + row) * 2 + 1] = p1 + b3[1];
    }
}

// ---------------------------------------------------------------------------
// edge->node aggregation (bf16 in, fp32 out)
// ---------------------------------------------------------------------------
__global__ __launch_bounds__(256)
void agg_k(const unsigned short* __restrict__ X2, float* __restrict__ outv)
{
    const int g = blockIdx.x * 256 + threadIdx.x;   // over MV*H
    const int h = g & 255;
    const int v = (g >> 8) & 31;
    const int b = g >> 13;
    float s = 0.f;
    #pragma unroll
    for (int snd = 0; snd < 32; ++snd) {
        if (snd == v) continue;
        const int e = snd * 31 + v - (snd < v ? 1 : 0);
        s += bf2f(X2[((size_t)b * E_ + e) * H_ + h]);
    }
    outv[g] = s * (1.f / 31.f);
}

// ---------------------------------------------------------------------------
extern "C" void kernel_launch(void* const* d_in, const int* in_sizes, int n_in,
                              void* d_out, int out_size, void* d_ws, size_t ws_size,
                              hipStream_t stream)
{
    const float* inputs = (const float*)d_in[0];
    const float* h0     = (const float*)d_in[1];
    const float* c0     = (const float*)d_in[2];
    const float* m1w1 = (const float*)d_in[3];  const float* m1b1 = (const float*)d_in[4];
    const float* m1w2 = (const float*)d_in[5];  const float* m1b2 = (const float*)d_in[6];
    const float* m1w3 = (const float*)d_in[7];  const float* m1b3 = (const float*)d_in[8];
    const float* m2w1 = (const float*)d_in[9];  const float* m2b1 = (const float*)d_in[10];
    const float* m2w2 = (const float*)d_in[11]; const float* m2b2 = (const float*)d_in[12];
    const float* m2w3 = (const float*)d_in[13]; const float* m2b3 = (const float*)d_in[14];
    const float* m3w1 = (const float*)d_in[15]; const float* m3b1 = (const float*)d_in[16];
    const float* m3w2 = (const float*)d_in[17]; const float* m3b2 = (const float*)d_in[18];
    const float* m3w3 = (const float*)d_in[19]; const float* m3b3 = (const float*)d_in[20];
    const float* m4w1 = (const float*)d_in[21]; const float* m4b1 = (const float*)d_in[22];
    const float* m4w2 = (const float*)d_in[23]; const float* m4b2 = (const float*)d_in[24];
    const float* m4w3 = (const float*)d_in[25]; const float* m4b3 = (const float*)d_in[26];
    const float* wih  = (const float*)d_in[27]; const float* whh  = (const float*)d_in[28];
    const float* bih  = (const float*)d_in[29]; const float* bhh  = (const float*)d_in[30];
    const float* pw1  = (const float*)d_in[31]; const float* pb1  = (const float*)d_in[32];
    const float* pw2  = (const float*)d_in[33]; const float* pb2  = (const float*)d_in[34];
    const float* pw3  = (const float*)d_in[35]; const float* pb3  = (const float*)d_in[36];

    float* out   = (float*)d_out;
    float* prior = out;
    float* h1    = out + (size_t)ME * 2;
    float* c1    = h1 + (size_t)ME * H_;

    // workspace layout
    float* S0 = (float*)d_ws;                 // 4 node fp32 buffers [MV,256]
    float* S1 = S0 + (size_t)MV * H_;
    float* S2 = S1 + (size_t)MV * H_;
    float* S3 = S2 + (size_t)MV * H_;
    unsigned short* EA = (unsigned short*)(S3 + (size_t)MV * H_);  // X2 bf16 [ME,256]
    unsigned short* EB = EA + (size_t)ME * H_;                     // h0 bf16
    unsigned short* EC = EB + (size_t)ME * H_;                     // h1 bf16
    unsigned short* CW = EC + (size_t)ME * H_;     // bf16 weights, contiguous
    unsigned short* cw22 = CW;                     // 7 x 65536
    unsigned short* cw23 = CW + 1 * 65536;
    unsigned short* cw41 = CW + 2 * 65536;
    unsigned short* cw42 = CW + 3 * 65536;
    unsigned short* cw43 = CW + 4 * 65536;
    unsigned short* cpw1 = CW + 5 * 65536;
    unsigned short* cpw2 = CW + 6 * 65536;
    unsigned short* cIH  = CW + 7 * 65536;         // cwih(262144) + cwhh(262144)
    unsigned short* cwih = cIH;
    unsigned short* cwhh = cIH + 262144;

    const dim3 blk(256);
    const dim3 gV(MV / 64, 4);      // node fp32 GEMMs
    const dim3 gC(ME / 64);         // fused edge chains (1984 blocks)

    // weight + h0 conversions (3 launches)
    convW7_k<<<dim3(64, 7), blk, 0, stream>>>(m2w2, m2w3, m4w1, m4w2, m4w3, pw1, pw2, CW);
    convIH_k<<<dim3(256, 2), blk, 0, stream>>>(wih, whh, cIH);
    f2b_k<<<ME * H_ / 1024, blk, 0, stream>>>(h0, EB, ME * H_ / 4);

    // MLP1 (node, fp32): inputs -> S0 -> S1 -> S0 (=X1)
    gemm_k<<<gV, blk, 0, stream>>>(inputs, 64, m1w1, 64, m1b1, S0, MV, 256, 64, 1);
    gemm_k<<<gV, blk, 0, stream>>>(S0, 256, m1w2, 256, m1b2, S1, MV, 256, 256, 1);
    gemm_k<<<gV, blk, 0, stream>>>(S1, 256, m1w3, 256, m1b3, S0, MV, 256, 256, 0);

    // Ys / Yr projections (node, fp32)
    gemm_k<<<gV, blk, 0, stream>>>(S0, 256, m2w1,       512, nullptr, S2, MV, 256, 256, 0);
    gemm_k<<<gV, blk, 0, stream>>>(S0, 256, m2w1 + 256, 512, nullptr, S3, MV, 256, 256, 0);

    // fused MLP2 chain -> X2 (EA)
    chain1_k<<<gC, blk, 0, stream>>>(S2, S3, m2b1, cw22, m2b2, cw23, m2b3, EA);

    // aggregate -> S0 ; MLP3 (node, fp32) -> S1 (=X3)
    agg_k<<<MV * H_ / 256, blk, 0, stream>>>(EA, S0);
    gemm_k<<<gV, blk, 0, stream>>>(S0, 256, m3w1, 256, m3b1, S1, MV, 256, 256, 1);
    gemm_k<<<gV, blk, 0, stream>>>(S1, 256, m3w2, 256, m3b2, S0, MV, 256, 256, 1);
    gemm_k<<<gV, blk, 0, stream>>>(S0, 256, m3w3, 256, m3b3, S1, MV, 256, 256, 0);

    // Zs / Zr projections (node, fp32)
    gemm_k<<<gV, blk, 0, stream>>>(S1, 256, m4w1,       768, nullptr, S2, MV, 256, 256, 0);
    gemm_k<<<gV, blk, 0, stream>>>(S1, 256, m4w1 + 256, 768, nullptr, S3, MV, 256, 256, 0);

    // fused MLP4 + LSTM chain: h1,c1 -> d_out, h1 bf16 -> EC
    chain2_k<<<gC, blk, 0, stream>>>(EA, cw41, m4b1, cw42, m4b2, cw43, m4b3,
                                     S2, S3, EB, cwih, cwhh, bih, bhh, c0, h1, c1, EC);

    // fused prior chain -> prior
    prior_k<<<gC, blk, 0, stream>>>(EC, cpw1, pb1, cpw2, pb2, pw3, pb3, prior);
}